// Round 5
// baseline (2668.015 us; speedup 1.0000x reference)
//
#include <hip/hip_runtime.h>
#include <cstddef>
#include <cmath>
#include <utility>

#define B_ 16
#define LQ_ 300
#define D_ 256
#define NH_ 8
#define HD_ 32
#define FF_ 1024
#define NBIN_ 33
#define NC_ 80
#define SUMP_ 12
#define TOT_ (NH_*SUMP_)   // 96
#define STOT_ 8400
#define R_ (B_*LQ_)        // 4800
#define NLAYERS_ 6

typedef short bf16x8 __attribute__((ext_vector_type(8)));
typedef float f32x4  __attribute__((ext_vector_type(4)));

static __device__ __forceinline__ short f2bf(float x) {
  union { float f; unsigned u; } v; v.f = x;
  unsigned r = v.u + 0x7fffu + ((v.u >> 16) & 1u);   // RNE
  return (short)(r >> 16);
}
static __device__ __forceinline__ float bf2f(short s) {
  union { unsigned u; float f; } v; v.u = ((unsigned)(unsigned short)s) << 16; return v.f;
}

// ---------------------------------------------------------------------------
// Weight convert+transpose: W [K,N] fp32 -> Wt [N,K] bf16 at out-stride.
// ---------------------------------------------------------------------------
__launch_bounds__(256)
__global__ void wconv_kernel(const float* __restrict__ W, short* __restrict__ Wt,
                             int K, int N, size_t ostride) {
  __shared__ float t[32][33];
  const float* Wl = W + (size_t)blockIdx.z * K * N;
  short* Wtl = Wt + (size_t)blockIdx.z * ostride;
  int k0 = blockIdx.x * 32, n0 = blockIdx.y * 32;
  int tr = threadIdx.x >> 5, tc = threadIdx.x & 31;
  #pragma unroll
  for (int i = 0; i < 4; ++i) {
    int k = k0 + tr + i * 8, n = n0 + tc;
    t[tr + i * 8][tc] = (k < K && n < N) ? Wl[(size_t)k * N + n] : 0.f;
  }
  __syncthreads();
  #pragma unroll
  for (int i = 0; i < 4; ++i) {
    int n = n0 + tr + i * 8, k = k0 + tc;
    if (n < N && k < K) Wtl[(size_t)n * K + k] = f2bf(t[tc][tr + i * 8]);
  }
}

// memory fp32 [B,S,256] -> bf16 head-major [B,NH,S,32]
__launch_bounds__(256)
__global__ void memconv_kernel(const float* __restrict__ mem, short* __restrict__ mb) {
  int gs = blockIdx.x * 4 + (threadIdx.x >> 6);
  int c  = (threadIdx.x & 63) * 4;
  int b = gs / STOT_, s = gs - b * STOT_;
  float4 v = *(const float4*)(mem + (size_t)gs * 256 + c);
  int h = c >> 5, cc = c & 31;
  short4 o; o.x = f2bf(v.x); o.y = f2bf(v.y); o.z = f2bf(v.z); o.w = f2bf(v.w);
  *(short4*)(mb + (((size_t)(b * 8 + h) * STOT_ + s) * 32) + cc) = o;
}

// ---------------------------------------------------------------------------
// Barrier-free bf16 MFMA GEMM, templated K.
// ACT: 0 none,1 relu,2 silu,3 sigmoid,4 clip10
// ---------------------------------------------------------------------------
template<int ACT, int KT>
__launch_bounds__(256)
__global__ void bgemm(const short* __restrict__ A, const short* __restrict__ A2, int N2,
                      const short* __restrict__ Acat, int KA,
                      const short* __restrict__ Wt, const float* __restrict__ bias,
                      const float* __restrict__ Cadd, float* __restrict__ Cf,
                      short* __restrict__ Cbf, int M, int N) {
  const int bm = blockIdx.y * 64, bn = blockIdx.x * 64;
  const int tid = threadIdx.x, wid = tid >> 6, lane = tid & 63;
  const int wm = (wid >> 1) * 32, wn = (wid & 1) * 32;
  const int lr = lane & 15, lq = lane >> 4;
  const short* Ab = (A2 && bn >= N2) ? A2 : A;
  const int lda = Acat ? KA : KT;
  const int ldb = KT - KA;
  const int r0 = bm + wm + lr, r1 = r0 + 16;
  const int n0 = bn + wn + lr, n1 = n0 + 16;
  const bool v0 = n0 < N, v1 = n1 < N;
  const short* w0p = Wt + (size_t)(v0 ? n0 : 0) * KT + lq * 8;
  const short* w1p = Wt + (size_t)(v1 ? n1 : 0) * KT + lq * 8;
  f32x4 acc[2][2];
  #pragma unroll
  for (int i = 0; i < 2; ++i)
    #pragma unroll
    for (int j = 0; j < 2; ++j) acc[i][j] = (f32x4){0.f, 0.f, 0.f, 0.f};

  #pragma unroll 4
  for (int k0 = 0; k0 < KT; k0 += 32) {
    const short* src; int ko, ld;
    if (Acat && k0 >= KA) { src = Acat; ko = k0 - KA; ld = ldb; }
    else                  { src = Ab;   ko = k0;      ld = lda; }
    bf16x8 a0 = *(const bf16x8*)(src + (size_t)r0 * ld + ko + lq * 8);
    bf16x8 a1 = *(const bf16x8*)(src + (size_t)r1 * ld + ko + lq * 8);
    bf16x8 w0 = *(const bf16x8*)(w0p + k0);
    bf16x8 w1 = *(const bf16x8*)(w1p + k0);
    acc[0][0] = __builtin_amdgcn_mfma_f32_16x16x32_bf16(a0, w0, acc[0][0], 0, 0, 0);
    acc[0][1] = __builtin_amdgcn_mfma_f32_16x16x32_bf16(a0, w1, acc[0][1], 0, 0, 0);
    acc[1][0] = __builtin_amdgcn_mfma_f32_16x16x32_bf16(a1, w0, acc[1][0], 0, 0, 0);
    acc[1][1] = __builtin_amdgcn_mfma_f32_16x16x32_bf16(a1, w1, acc[1][1], 0, 0, 0);
  }
  #pragma unroll
  for (int ti = 0; ti < 2; ++ti)
    #pragma unroll
    for (int tj = 0; tj < 2; ++tj) {
      int gn = bn + wn + tj * 16 + lr;
      if (gn >= N) continue;
      float bv = bias[gn];
      #pragma unroll
      for (int r = 0; r < 4; ++r) {
        int gm = bm + wm + ti * 16 + lq * 4 + r;
        size_t idx = (size_t)gm * N + gn;
        float v = acc[ti][tj][r] + bv;
        if (Cadd) v += Cadd[idx];
        if (ACT == 1) v = fmaxf(v, 0.f);
        if (ACT == 2) v = v / (1.f + __expf(-v));
        if (ACT == 3) v = 1.f / (1.f + __expf(-v));
        if (ACT == 4) v = fminf(fmaxf(v, -10.f), 10.f);
        if (Cf)  Cf[idx] = v;
        if (Cbf) Cbf[idx] = f2bf(v);
      }
    }
}

// ---------------------------------------------------------------------------
// Fused GEMM (N=256) + LayerNorm. Block = 32 rows x 256 cols, 4 waves
// (wave = 16 rows x 128 cols = 8 mfma tiles). Grid = 150.
// x = resid + (A@Wt + bias)  [MODE1: clip +-65504]
// v = LN(x)*gamma+beta -> out(fp32), outbf(bf16)
// MODE0: oqbf = bf16(v + qp)          (post self-attn LN)
// MODE1: oqbf = bf16(v + prev_old); prev = v   (post FFN LN)
// ---------------------------------------------------------------------------
template<int KT, int MODE>
__launch_bounds__(256)
__global__ void gemm_ln(const short* __restrict__ A, const short* __restrict__ Wt,
                        const float* __restrict__ bias, const float* __restrict__ resid,
                        const float* __restrict__ gamma, const float* __restrict__ beta,
                        const float* __restrict__ qp, float* __restrict__ prev,
                        float* __restrict__ outf, short* __restrict__ outbf,
                        short* __restrict__ oqbf) {
  __shared__ float ssum[32][2];
  __shared__ float ssq[32][2];
  const int m0 = blockIdx.x * 32;
  const int tid = threadIdx.x, wid = tid >> 6, lane = tid & 63;
  const int rw = (wid & 1) * 16, cw = (wid >> 1) * 128;
  const int lr = lane & 15, lq = lane >> 4;
  const int arow = m0 + rw + lr;
  f32x4 acc[8];
  #pragma unroll
  for (int t = 0; t < 8; ++t) acc[t] = (f32x4){0.f, 0.f, 0.f, 0.f};
  #pragma unroll 2
  for (int k0 = 0; k0 < KT; k0 += 32) {
    bf16x8 a = *(const bf16x8*)(A + (size_t)arow * KT + k0 + lq * 8);
    #pragma unroll
    for (int t = 0; t < 8; ++t) {
      bf16x8 w = *(const bf16x8*)(Wt + (size_t)(cw + t * 16 + lr) * KT + k0 + lq * 8);
      acc[t] = __builtin_amdgcn_mfma_f32_16x16x32_bf16(a, w, acc[t], 0, 0, 0);
    }
  }
  // x = resid + gemm + bias ; stats
  float s[4] = {0.f, 0.f, 0.f, 0.f}, q[4] = {0.f, 0.f, 0.f, 0.f};
  #pragma unroll
  for (int t = 0; t < 8; ++t) {
    int col = cw + t * 16 + lr;
    float bv = bias[col];
    #pragma unroll
    for (int rr = 0; rr < 4; ++rr) {
      int rowg = m0 + rw + lq * 4 + rr;
      float x = acc[t][rr] + bv + resid[(size_t)rowg * 256 + col];
      if (MODE == 1) x = fminf(fmaxf(x, -65504.f), 65504.f);
      acc[t][rr] = x;
      s[rr] += x; q[rr] += x * x;
    }
  }
  #pragma unroll
  for (int m = 1; m < 16; m <<= 1)
    #pragma unroll
    for (int rr = 0; rr < 4; ++rr) { s[rr] += __shfl_xor(s[rr], m); q[rr] += __shfl_xor(q[rr], m); }
  if (lr == 0)
    #pragma unroll
    for (int rr = 0; rr < 4; ++rr) {
      ssum[rw + lq * 4 + rr][wid >> 1] = s[rr];
      ssq[rw + lq * 4 + rr][wid >> 1] = q[rr];
    }
  __syncthreads();
  float mu[4], rs[4];
  #pragma unroll
  for (int rr = 0; rr < 4; ++rr) {
    int rl = rw + lq * 4 + rr;
    float sm = ssum[rl][0] + ssum[rl][1];
    float sq = ssq[rl][0] + ssq[rl][1];
    float m_ = sm * (1.f / 256.f);
    float var = sq * (1.f / 256.f) - m_ * m_;
    mu[rr] = m_; rs[rr] = rsqrtf(var + 1e-5f);
  }
  #pragma unroll
  for (int t = 0; t < 8; ++t) {
    int col = cw + t * 16 + lr;
    float g = gamma[col], be = beta[col];
    #pragma unroll
    for (int rr = 0; rr < 4; ++rr) {
      int rowg = m0 + rw + lq * 4 + rr;
      size_t idx = (size_t)rowg * 256 + col;
      float v = (acc[t][rr] - mu[rr]) * rs[rr] * g + be;
      outf[idx] = v;
      outbf[idx] = f2bf(v);
      if (MODE == 0) {
        oqbf[idx] = f2bf(v + qp[idx]);
      } else {
        float po = prev[idx];
        oqbf[idx] = f2bf(v + po);
        prev[idx] = v;
      }
    }
  }
}

// ---------------------------------------------------------------------------
// Fused qp MLP: hid = silu(ref@W1+b1) in LDS; qp = clip(hid@W2t+b2);
// oqbf = bf16(qp + output). Block = 64 rows, grid = 75.
// ---------------------------------------------------------------------------
__launch_bounds__(256)
__global__ void qp_mlp(const float* __restrict__ ref, const float* __restrict__ W1,
                       const float* __restrict__ b1, const short* __restrict__ W2t,
                       const float* __restrict__ b2, const float* __restrict__ output,
                       float* __restrict__ qpout, short* __restrict__ oqbf) {
  __shared__ short sh[64 * 520];
  const int m0 = blockIdx.x * 64;
  const int tid = threadIdx.x;
  for (int i = tid; i < 64 * 512; i += 256) {
    int r = i >> 9, n = i & 511;
    float4 rv = *(const float4*)(ref + (size_t)(m0 + r) * 4);
    float v = b1[n] + rv.x * W1[n] + rv.y * W1[512 + n] + rv.z * W1[1024 + n]
            + rv.w * W1[1536 + n];
    v = v / (1.f + __expf(-v));
    sh[r * 520 + n] = f2bf(v);
  }
  __syncthreads();
  const int wid = tid >> 6, lane = tid & 63;
  const int lr = lane & 15, lq = lane >> 4;
  f32x4 acc[16];
  #pragma unroll
  for (int t = 0; t < 16; ++t) acc[t] = (f32x4){0.f, 0.f, 0.f, 0.f};
  #pragma unroll 2
  for (int k0 = 0; k0 < 512; k0 += 32) {
    bf16x8 a = *(const bf16x8*)&sh[(wid * 16 + lr) * 520 + k0 + lq * 8];
    #pragma unroll
    for (int t = 0; t < 16; ++t) {
      bf16x8 w = *(const bf16x8*)(W2t + (size_t)(t * 16 + lr) * 512 + k0 + lq * 8);
      acc[t] = __builtin_amdgcn_mfma_f32_16x16x32_bf16(a, w, acc[t], 0, 0, 0);
    }
  }
  #pragma unroll
  for (int t = 0; t < 16; ++t) {
    int col = t * 16 + lr;
    float bv = b2[col];
    #pragma unroll
    for (int rr = 0; rr < 4; ++rr) {
      int rowg = m0 + wid * 16 + lq * 4 + rr;
      size_t idx = (size_t)rowg * 256 + col;
      float v = fminf(fmaxf(acc[t][rr] + bv, -10.f), 10.f);
      qpout[idx] = v;
      oqbf[idx] = f2bf(v + output[idx]);
    }
  }
}

// ---------------------------------------------------------------------------
// Fused bb3 GEMM (64 rows x 132 cols per block) + c_prev add + corner
// softmax/dist + distance2bbox. Grid = 75.
// ---------------------------------------------------------------------------
__launch_bounds__(256)
__global__ void bb3_bbox(const short* __restrict__ A, const short* __restrict__ Wt,
                         const float* __restrict__ bias, const float* __restrict__ cprev,
                         float* __restrict__ ccur, const float* __restrict__ refi,
                         float* __restrict__ refn) {
  __shared__ float S[64][136];
  __shared__ float Dd[64][4];
  const int m0 = blockIdx.x * 64;
  const int tid = threadIdx.x, wid = tid >> 6, lane = tid & 63;
  const int lr = lane & 15, lq = lane >> 4;
  const int arow = m0 + wid * 16 + lr;
  f32x4 acc[9];
  #pragma unroll
  for (int t = 0; t < 9; ++t) acc[t] = (f32x4){0.f, 0.f, 0.f, 0.f};
  #pragma unroll 2
  for (int k0 = 0; k0 < 256; k0 += 32) {
    bf16x8 a = *(const bf16x8*)(A + (size_t)arow * 256 + k0 + lq * 8);
    #pragma unroll
    for (int t = 0; t < 9; ++t) {
      bf16x8 w = *(const bf16x8*)(Wt + (size_t)(t * 16 + lr) * 256 + k0 + lq * 8);
      acc[t] = __builtin_amdgcn_mfma_f32_16x16x32_bf16(a, w, acc[t], 0, 0, 0);
    }
  }
  #pragma unroll
  for (int t = 0; t < 9; ++t) {
    int col = t * 16 + lr;
    if (col >= 132) continue;
    float bv = bias[col];
    #pragma unroll
    for (int rr = 0; rr < 4; ++rr) {
      int rl = wid * 16 + lq * 4 + rr;
      int rowg = m0 + rl;
      float v = acc[t][rr] + bv + cprev[(size_t)rowg * 132 + col];
      ccur[(size_t)rowg * 132 + col] = v;
      S[rl][col] = v;
    }
  }
  __syncthreads();
  // phase 2: per (row, side) softmax over 33 bins dot proj
  {
    int rl = tid >> 2, side = tid & 3;
    float proj[NBIN_];
    proj[0] = -4.f; proj[16] = 0.f; proj[32] = 4.f;
    const float step = powf(3.f, 1.f / 15.f);
    float pw = 1.f;
    #pragma unroll
    for (int i = 1; i <= 15; ++i) { pw *= step; proj[16 + i] = pw - 1.f; proj[16 - i] = 1.f - pw; }
    const float* cp = &S[rl][side * NBIN_];
    float m = -1e30f;
    #pragma unroll
    for (int j = 0; j < NBIN_; ++j) m = fmaxf(m, cp[j]);
    float sum = 0.f, dot = 0.f;
    #pragma unroll
    for (int j = 0; j < NBIN_; ++j) { float e = __expf(cp[j] - m); sum += e; dot += e * proj[j]; }
    Dd[rl][side] = dot / sum;
  }
  __syncthreads();
  if (tid < 64) {
    int rowg = m0 + tid;
    float px = refi[rowg * 4], py = refi[rowg * 4 + 1];
    float qw = refi[rowg * 4 + 2] * 0.25f, qh = refi[rowg * 4 + 3] * 0.25f;
    float x1 = px - (2.f + Dd[tid][0]) * qw, y1 = py - (2.f + Dd[tid][1]) * qh;
    float x2 = px + (2.f + Dd[tid][2]) * qw, y2 = py + (2.f + Dd[tid][3]) * qh;
    refn[rowg * 4 + 0] = (x1 + x2) * 0.5f;
    refn[rowg * 4 + 1] = (y1 + y2) * 0.5f;
    refn[rowg * 4 + 2] = x2 - x1;
    refn[rowg * 4 + 3] = y2 - y1;
  }
}

// ---------------------------------------------------------------------------
// pb3 (N=4) + prebb fused: ref_init = sigmoid(h2@pb3 + b + inv_sigmoid(ref))
// ---------------------------------------------------------------------------
__launch_bounds__(256)
__global__ void pb3_prebb(const short* __restrict__ A, const short* __restrict__ Wt,
                          const float* __restrict__ bias, const float* __restrict__ refc,
                          float* __restrict__ refinit) {
  int i = blockIdx.x * 256 + threadIdx.x;
  if (i >= R_ * 4) return;
  int row = i >> 2, n = i & 3;
  const short* ap = A + (size_t)row * 256;
  const short* wp = Wt + (size_t)n * 256;
  float dot = 0.f;
  #pragma unroll 8
  for (int k = 0; k < 256; ++k) dot += bf2f(ap[k]) * bf2f(wp[k]);
  float pre = dot + bias[n];
  float x = fminf(fmaxf(refc[i], 1e-5f), 1.f - 1e-5f);
  float is = logf(x) - log1pf(-x);
  refinit[i] = 1.f / (1.f + __expf(-(pre + is)));
}

// ---------------------------------------------------------------------------
// LayerNorm MODE2 (gateway): x = g1*a + g2*b
// ---------------------------------------------------------------------------
__launch_bounds__(256)
__global__ void ln2_kernel(float* __restrict__ out, short* __restrict__ outbf,
                           const float* __restrict__ a, const float* __restrict__ b,
                           const float* __restrict__ g12,
                           const float* __restrict__ gamma, const float* __restrict__ beta) {
  const int row = blockIdx.x, c = threadIdx.x;
  const size_t off = (size_t)row * D_ + c;
  float g1 = g12[(size_t)row * 2 * D_ + c];
  float g2 = g12[(size_t)row * 2 * D_ + D_ + c];
  float x = g1 * a[off] + g2 * b[off];
  __shared__ float red[8];
  float s = x;
  #pragma unroll
  for (int o = 32; o; o >>= 1) s += __shfl_down(s, o);
  if ((c & 63) == 0) red[c >> 6] = s;
  __syncthreads();
  float mu = (red[0] + red[1] + red[2] + red[3]) * (1.f / D_);
  float dd = x - mu;
  float s2 = dd * dd;
  #pragma unroll
  for (int o = 32; o; o >>= 1) s2 += __shfl_down(s2, o);
  if ((c & 63) == 0) red[4 + (c >> 6)] = s2;
  __syncthreads();
  float var = (red[4] + red[5] + red[6] + red[7]) * (1.f / D_);
  float v = dd * rsqrtf(var + 1e-5f) * gamma[c] + beta[c];
  out[off] = v;
  outbf[off] = f2bf(v);
}

// ---------------------------------------------------------------------------
// MFMA self-attention. Block per (b,h,half).
// ---------------------------------------------------------------------------
__launch_bounds__(256)
__global__ void attn3_kernel(const short* __restrict__ qkv, short* __restrict__ O) {
  __shared__ short Kb[304][40];
  __shared__ short Vt[32][328];
  __shared__ short Pw[4][16][328];
  const int half = blockIdx.x & 1, bh = blockIdx.x >> 1;
  const int h = bh & 7, b = bh >> 3;
  const int tid = threadIdx.x;
  const short* QKVb = qkv + (size_t)b * LQ_ * 768;
  for (int idx = tid; idx < 304 * 4; idx += 256) {
    int row = idx >> 2, seg = (idx & 3) * 8;
    bf16x8 v = (row < 300) ? *(const bf16x8*)(QKVb + (size_t)row * 768 + 256 + h * 32 + seg)
                           : (bf16x8){0,0,0,0,0,0,0,0};
    *(bf16x8*)&Kb[row][seg] = v;
  }
  for (int idx = tid; idx < 300 * 4; idx += 256) {
    int row = idx >> 2, seg = (idx & 3) * 8;
    bf16x8 v = *(const bf16x8*)(QKVb + (size_t)row * 768 + 512 + h * 32 + seg);
    #pragma unroll
    for (int j = 0; j < 8; ++j) Vt[seg + j][row] = v[j];
  }
  for (int idx = tid; idx < 32 * 20; idx += 256) Vt[idx / 20][300 + idx % 20] = 0;
  for (int idx = tid; idx < 4 * 16 * 16; idx += 256)
    Pw[idx >> 8][(idx >> 4) & 15][304 + (idx & 15)] = 0;
  __syncthreads();

  const int wid = tid >> 6, lane = tid & 63;
  const int lr = lane & 15, lq = lane >> 4;
  short (*Pl)[328] = Pw[wid];
  const float scale = 0.17677669529663687f;

  for (int qt = wid; qt < 10; qt += 4) {
    const int q0 = half * 150 + qt * 16;
    int qrow = q0 + lr; if (qrow > 299) qrow = 299;
    bf16x8 af_q = *(const bf16x8*)(QKVb + (size_t)qrow * 768 + h * 32 + lq * 8);
    f32x4 s[19];
    #pragma unroll
    for (int t = 0; t < 19; ++t) {
      bf16x8 bk = *(const bf16x8*)&Kb[t * 16 + lr][lq * 8];
      s[t] = __builtin_amdgcn_mfma_f32_16x16x32_bf16(af_q, bk, (f32x4){0.f,0.f,0.f,0.f}, 0, 0, 0);
    }
    #pragma unroll
    for (int t = 0; t < 19; ++t)
      #pragma unroll
      for (int r = 0; r < 4; ++r) s[t][r] *= scale;
    if (lr >= 12) { s[18][0] = s[18][1] = s[18][2] = s[18][3] = -1e30f; }
    float l[4];
    #pragma unroll
    for (int r = 0; r < 4; ++r) {
      float mm = -1e30f;
      #pragma unroll
      for (int t = 0; t < 19; ++t) mm = fmaxf(mm, s[t][r]);
      #pragma unroll
      for (int x = 1; x < 16; x <<= 1) mm = fmaxf(mm, __shfl_xor(mm, x));
      float ll = 0.f;
      #pragma unroll
      for (int t = 0; t < 19; ++t) { float p = __expf(s[t][r] - mm); s[t][r] = p; ll += p; }
      #pragma unroll
      for (int x = 1; x < 16; x <<= 1) ll += __shfl_xor(ll, x);
      l[r] = ll;
    }
    #pragma unroll
    for (int t = 0; t < 19; ++t)
      #pragma unroll
      for (int r = 0; r < 4; ++r) Pl[lq * 4 + r][t * 16 + lr] = f2bf(s[t][r]);
    f32x4 o0 = (f32x4){0.f,0.f,0.f,0.f}, o1 = (f32x4){0.f,0.f,0.f,0.f};
    #pragma unroll
    for (int c = 0; c < 10; ++c) {
      bf16x8 ap = *(const bf16x8*)&Pl[lr][c * 32 + lq * 8];
      bf16x8 v0 = *(const bf16x8*)&Vt[lr][c * 32 + lq * 8];
      bf16x8 v1 = *(const bf16x8*)&Vt[16 + lr][c * 32 + lq * 8];
      o0 = __builtin_amdgcn_mfma_f32_16x16x32_bf16(ap, v0, o0, 0, 0, 0);
      o1 = __builtin_amdgcn_mfma_f32_16x16x32_bf16(ap, v1, o1, 0, 0, 0);
    }
    #pragma unroll
    for (int r = 0; r < 4; ++r) {
      int q = q0 + lq * 4 + r;
      if (q >= 300) continue;
      float inv = 1.f / l[r];
      size_t ob = (size_t)(b * LQ_ + q) * 256 + h * 32;
      O[ob + lr]      = f2bf(o0[r] * inv);
      O[ob + 16 + lr] = f2bf(o1[r] * inv);
    }
  }
}

// ---------------------------------------------------------------------------
// Deformable sampling, branch-free taps (clamped idx, zeroed weights).
// ---------------------------------------------------------------------------
template<int BF16MEM>
__launch_bounds__(256)
__global__ void deform_kernel(const void* __restrict__ memv, const float* __restrict__ offaw,
                              const float* __restrict__ refp,
                              float* __restrict__ t2, short* __restrict__ t2bf) {
  const int bi = blockIdx.x;
  const int row = (bi & 7) * 600 + (bi >> 3);   // XCD locality swizzle
  const int b = row / LQ_;
  const int tid = threadIdx.x;
  const int h = tid >> 5, c = tid & 31;
  const float rx = refp[row * 4 + 0], ry = refp[row * 4 + 1];
  const float rw = refp[row * 4 + 2], rh = refp[row * 4 + 3];
  const float* awp = offaw + (size_t)row * 288 + 192 + h * SUMP_;
  float wv[SUMP_];
  float wmax = -1e30f;
  #pragma unroll
  for (int p = 0; p < SUMP_; ++p) { wv[p] = awp[p]; wmax = fmaxf(wmax, wv[p]); }
  float wsum = 0.f;
  #pragma unroll
  for (int p = 0; p < SUMP_; ++p) { wv[p] = __expf(wv[p] - wmax); wsum += wv[p]; }
  const float winv = 1.f / wsum;
  const float* op = offaw + (size_t)row * 288 + h * (SUMP_ * 2);
  const short* mb16 = BF16MEM ? ((const short*)memv + ((size_t)(b * 8 + h) * STOT_) * 32 + c) : nullptr;
  const float* mb32 = BF16MEM ? nullptr : ((const float*)memv + (size_t)b * STOT_ * 256 + h * 32 + c);
  float acc = 0.f;
  #pragma unroll
  for (int p = 0; p < SUMP_; ++p) {
    const int lvl = p >> 2;
    const int Wl = (lvl == 0) ? 80 : ((lvl == 1) ? 40 : 20);
    const int s0 = (lvl == 0) ? 0 : ((lvl == 1) ? 6400 : 8000);
    float lx = rx + op[2 * p]     * 0.125f * rw;
    float ly = ry + op[2 * p + 1] * 0.125f * rh;
    float x = lx * Wl - 0.5f, y = ly * Wl - 0.5f;
    float xf = floorf(x), yf = floorf(y);
    int x0 = (int)xf, y0 = (int)yf;
    float wx = x - xf, wy = y - yf;
    int x0c = min(max(x0, 0), Wl - 1), x1c = min(max(x0 + 1, 0), Wl - 1);
    int y0c = min(max(y0, 0), Wl - 1), y1c = min(max(y0 + 1, 0), Wl - 1);
    float wx0 = (x0 >= 0 && x0 < Wl) ? (1.f - wx) : 0.f;
    float wx1 = (x0 + 1 >= 0 && x0 + 1 < Wl) ? wx : 0.f;
    float wy0 = (y0 >= 0 && y0 < Wl) ? (1.f - wy) : 0.f;
    float wy1 = (y0 + 1 >= 0 && y0 + 1 < Wl) ? wy : 0.f;
    float v;
    if (BF16MEM) {
      const short* mb = mb16 + (size_t)s0 * 32;
      v = wx0 * wy0 * bf2f(mb[(size_t)(y0c * Wl + x0c) * 32])
        + wx1 * wy0 * bf2f(mb[(size_t)(y0c * Wl + x1c) * 32])
        + wx0 * wy1 * bf2f(mb[(size_t)(y1c * Wl + x0c) * 32])
        + wx1 * wy1 * bf2f(mb[(size_t)(y1c * Wl + x1c) * 32]);
    } else {
      const float* mb = mb32 + (size_t)s0 * 256;
      v = wx0 * wy0 * mb[(size_t)(y0c * Wl + x0c) * 256]
        + wx1 * wy0 * mb[(size_t)(y0c * Wl + x1c) * 256]
        + wx0 * wy1 * mb[(size_t)(y1c * Wl + x0c) * 256]
        + wx1 * wy1 * mb[(size_t)(y1c * Wl + x1c) * 256];
    }
    acc += wv[p] * winv * v;
  }
  size_t off = (size_t)row * D_ + h * HD_ + c;
  t2[off] = acc;
  t2bf[off] = f2bf(acc);
}

// ---------------------------------------------------------------------------
// LQE head + final output assembly.
// ---------------------------------------------------------------------------
__launch_bounds__(64)
__global__ void lqe_kernel(const float* __restrict__ scores, const float* __restrict__ corners,
                           const float* __restrict__ w1, const float* __restrict__ b1,
                           const float* __restrict__ w2, const float* __restrict__ b2,
                           const float* __restrict__ inter, float* __restrict__ out) {
  const int row = blockIdx.x;
  const int tid = threadIdx.x;
  __shared__ float stat[20];
  __shared__ float lqe_s;
  if (tid < 4) {
    const float* cp = corners + (size_t)row * (4 * NBIN_) + tid * NBIN_;
    float m = -1e30f;
    for (int j = 0; j < NBIN_; ++j) m = fmaxf(m, cp[j]);
    float e[NBIN_]; float sum = 0.f;
    for (int j = 0; j < NBIN_; ++j) { e[j] = __expf(cp[j] - m); sum += e[j]; }
    float inv = 1.f / sum;
    float mean = 0.f;
    for (int t = 0; t < 4; ++t) {
      int bi = 0; float best = -1.f;
      for (int j = 0; j < NBIN_; ++j) if (e[j] > best) { best = e[j]; bi = j; }
      e[bi] = -2.f;
      float v = best * inv;
      stat[tid * 5 + t] = v; mean += v;
    }
    stat[tid * 5 + 4] = mean * 0.25f;
  }
  __syncthreads();
  float s = b1[tid];
  #pragma unroll
  for (int i = 0; i < 20; ++i) s += stat[i] * w1[i * 64 + tid];
  float hv = s / (1.f + __expf(-s));
  float v = hv * w2[tid];
  #pragma unroll
  for (int o = 32; o; o >>= 1) v += __shfl_down(v, o);
  if (tid == 0) lqe_s = v + b2[0];
  __syncthreads();
  if (tid < 4) out[(size_t)row * 84 + tid] = inter[row * 4 + tid];
  for (int c = tid; c < NC_; c += 64)
    out[(size_t)row * 84 + 4 + c] = scores[(size_t)row * NC_ + c] + lqe_s;
}

// ---------------------------------------------------------------------------
// small elementwise kernels
// ---------------------------------------------------------------------------
__global__ void fill0_kernel(float* __restrict__ p, int n) {
  int i = blockIdx.x * 256 + threadIdx.x; if (i < n) p[i] = 0.f;
}
__global__ void sigmoid_kernel(float* __restrict__ d, const float* __restrict__ s, int n) {
  int i = blockIdx.x * 256 + threadIdx.x; if (i < n) d[i] = 1.f / (1.f + __expf(-s[i]));
}
__global__ void initcvt_kernel(float* __restrict__ o, short* __restrict__ ob,
                               const float* __restrict__ t, int n4) {
  int i = blockIdx.x * 256 + threadIdx.x;
  if (i < n4) {
    float4 v = ((const float4*)t)[i];
    ((float4*)o)[i] = v;
    short4 s; s.x = f2bf(v.x); s.y = f2bf(v.y); s.z = f2bf(v.z); s.w = f2bf(v.w);
    ((short4*)ob)[i] = s;
  }
}
__global__ void bcat_kernel(const float* __restrict__ qb, const float* __restrict__ kb,
                            const float* __restrict__ vb, const float* __restrict__ ob,
                            const float* __restrict__ ab, float* __restrict__ qkvb,
                            float* __restrict__ offawb) {
  int i = blockIdx.x * 256 + threadIdx.x;
  if (i < NLAYERS_ * 768) {
    int l = i / 768, c = i % 768;
    qkvb[i] = (c < 256) ? qb[l * 256 + c] : (c < 512) ? kb[l * 256 + c - 256]
                        : vb[l * 256 + c - 512];
  }
  if (i < NLAYERS_ * 288) {
    int l = i / 288, c = i % 288;
    offawb[i] = (c < 192) ? ob[l * 192 + c] : ab[l * 96 + c - 192];
  }
}

// ---------------------------------------------------------------------------
// host orchestration
// ---------------------------------------------------------------------------
template<int KT>
static void launch_bgemm_k(hipStream_t st, const short* A, const short* A2, int N2,
                           const short* Acat, int KA, const short* Wt, const float* bias,
                           const float* Cadd, float* Cf, short* Cbf, int M, int N, int act) {
  dim3 g((N + 63) / 64, M / 64), blk(256);
  switch (act) {
    case 0: bgemm<0,KT><<<g, blk, 0, st>>>(A, A2, N2, Acat, KA, Wt, bias, Cadd, Cf, Cbf, M, N); break;
    case 1: bgemm<1,KT><<<g, blk, 0, st>>>(A, A2, N2, Acat, KA, Wt, bias, Cadd, Cf, Cbf, M, N); break;
    case 2: bgemm<2,KT><<<g, blk, 0, st>>>(A, A2, N2, Acat, KA, Wt, bias, Cadd, Cf, Cbf, M, N); break;
    case 3: bgemm<3,KT><<<g, blk, 0, st>>>(A, A2, N2, Acat, KA, Wt, bias, Cadd, Cf, Cbf, M, N); break;
    case 4: bgemm<4,KT><<<g, blk, 0, st>>>(A, A2, N2, Acat, KA, Wt, bias, Cadd, Cf, Cbf, M, N); break;
  }
}
static void launch_bgemm(hipStream_t st, const short* A, const short* A2, int N2,
                         const short* Acat, int KA, const short* Wt, const float* bias,
                         const float* Cadd, float* Cf, short* Cbf,
                         int M, int N, int K, int act) {
  if (K == 256)      launch_bgemm_k<256>(st, A, A2, N2, Acat, KA, Wt, bias, Cadd, Cf, Cbf, M, N, act);
  else if (K == 512) launch_bgemm_k<512>(st, A, A2, N2, Acat, KA, Wt, bias, Cadd, Cf, Cbf, M, N, act);
  else               launch_bgemm_k<1024>(st, A, A2, N2, Acat, KA, Wt, bias, Cadd, Cf, Cbf, M, N, act);
}

static void conv_w(hipStream_t st, const float* W, short* Wt, int K, int N, int L,
                   size_t ostride) {
  dim3 g((K + 31) / 32, (N + 31) / 32, L);
  wconv_kernel<<<g, 256, 0, st>>>(W, Wt, K, N, ostride);
}

static inline dim3 egrid(int n) { return dim3((n + 255) / 256); }

extern "C" void kernel_launch(void* const* d_in, const int* in_sizes, int n_in,
                              void* d_out, int out_size, void* d_ws, size_t ws_size,
                              hipStream_t stream) {
  const float* target     = (const float*)d_in[0];
  const float* ref_unact  = (const float*)d_in[1];
  const float* memory     = (const float*)d_in[2];
  const float* sa_qw = (const float*)d_in[3];  const float* sa_qb = (const float*)d_in[4];
  const float* sa_kw = (const float*)d_in[5];  const float* sa_kb = (const float*)d_in[6];
  const float* sa_vw = (const float*)d_in[7];  const float* sa_vb = (const float*)d_in[8];
  const float* sa_ow = (const float*)d_in[9];  const float* sa_ob = (const float*)d_in[10];
  const float* n1_g  = (const float*)d_in[11]; const float* n1_b  = (const float*)d_in[12];
  const float* off_w = (const float*)d_in[13]; const float* off_b = (const float*)d_in[14];
  const float* aw_w  = (const float*)d_in[15]; const float* aw_b  = (const float*)d_in[16];
  const float* gate_w= (const float*)d_in[17]; const float* gate_b= (const float*)d_in[18];
  const float* gn_g  = (const float*)d_in[19]; const float* gn_b  = (const float*)d_in[20];
  const float* ff1_w = (const float*)d_in[21]; const float* ff1_b = (const float*)d_in[22];
  const float* ff2_w = (const float*)d_in[23]; const float* ff2_b = (const float*)d_in[24];
  const float* n3_g  = (const float*)d_in[25]; const float* n3_b  = (const float*)d_in[26];
  const float* bb_w1 = (const float*)d_in[27]; const float* bb_b1 = (const float*)d_in[28];
  const float* bb_w2 = (const float*)d_in[29]; const float* bb_b2 = (const float*)d_in[30];
  const float* bb_w3 = (const float*)d_in[31]; const float* bb_b3 = (const float*)d_in[32];
  const float* sc_w  = (const float*)d_in[33]; const float* sc_b  = (const float*)d_in[34];
  const float* lqe_w1= (const float*)d_in[35]; const float* lqe_b1= (const float*)d_in[36];
  const float* lqe_w2= (const float*)d_in[37]; const float* lqe_b2= (const float*)d_in[38];
  const float* qp_w1 = (const float*)d_in[39]; const float* qp_b1 = (const float*)d_in[40];
  const float* qp_w2 = (const float*)d_in[41]; const float* qp_b2 = (const float*)d_in[42];
  const float* pb_w1 = (const float*)d_in[43]; const float* pb_b1 = (const float*)d_in[44];
  const float* pb_w2 = (const float*)d_in[45]; const float* pb_b2 = (const float*)d_in[46];
  const float* pb_w3 = (const float*)d_in[47]; const float* pb_b3 = (const float*)d_in[48];
  float* out = (float*)d_out;

  // ---- workspace: fp32 region ----
  float* ws = (float*)d_ws;
  size_t woff = 0;
  auto alloc = [&](size_t n) { float* p = ws + woff; woff += n; return p; };
  float* output   = alloc((size_t)R_ * D_);
  float* out_prev = alloc((size_t)R_ * D_);
  float* qp       = alloc((size_t)R_ * D_);
  float* t2       = alloc((size_t)R_ * D_);
  float* offawf   = alloc((size_t)R_ * 288);  // also scores
  float* U        = alloc((size_t)R_ * 512);  // qkv(bf)/g12(f32)/ffnhid(bf)
  float* corners0 = alloc((size_t)R_ * 4 * NBIN_);
  float* corners1 = alloc((size_t)R_ * 4 * NBIN_);
  float* refA     = alloc((size_t)R_ * 4);
  float* refB     = alloc((size_t)R_ * 4);
  float* ref_init = alloc((size_t)R_ * 4);
  float* qkvb     = alloc((size_t)NLAYERS_ * 768);
  float* offawb   = alloc((size_t)NLAYERS_ * 288);

  // ---- workspace: bf16 region ----
  short* sws = (short*)(ws + woff);
  size_t soff = 0;
  auto salloc = [&](size_t n) { short* p = sws + soff; soff += n; return p; };
  short* outbf = salloc((size_t)R_ * D_);
  short* oqbf  = salloc((size_t)R_ * D_);
  short* tbf   = salloc((size_t)R_ * D_);
  short* h1bf  = salloc((size_t)R_ * D_);
  short* h2bf  = salloc((size_t)R_ * D_);
  short* qp2t  = salloc((size_t)256 * 512);
  short* sqkvt = salloc((size_t)NLAYERS_ * 768 * 256);
  short* sowt  = salloc((size_t)NLAYERS_ * 256 * 256);
  short* soffawt = salloc((size_t)NLAYERS_ * 288 * 256);
  short* gatet = salloc((size_t)NLAYERS_ * 512 * 512);
  short* ff1t  = salloc((size_t)NLAYERS_ * 1024 * 256);
  short* ff2t  = salloc((size_t)NLAYERS_ * 256 * 1024);
  short* bb1t  = salloc((size_t)NLAYERS_ * 256 * 256);
  short* bb2t  = salloc((size_t)NLAYERS_ * 256 * 256);
  short* bb3t  = salloc((size_t)NLAYERS_ * 144 * 256);   // padded to 144 rows
  short* pb1t  = salloc((size_t)256 * 256);
  short* pb2t  = salloc((size_t)256 * 256);
  short* pb3t  = salloc((size_t)4 * 256);
  short* sct   = salloc((size_t)80 * 256);
  size_t base_bytes = woff * sizeof(float) + soff * sizeof(short);
  if (ws_size < base_bytes) return;
  const size_t memn = (size_t)B_ * STOT_ * 256;
  bool bf16mem = (ws_size >= base_bytes + memn * sizeof(short));
  short* membf = sws + soff;

  short* qkv    = (short*)U;
  short* ffnhid = (short*)U;
  float* g12    = U;
  float* scores = offawf;

  float* c_prev = corners0; float* c_cur = corners1;
  float* ref_cur = refA;    float* ref_nxt = refB;

  // ---- weight prep ----
  conv_w(stream, qp_w2, qp2t, 512, 256, 1, 0);
  conv_w(stream, sa_qw, sqkvt,               256, 256, NLAYERS_, 768 * 256);
  conv_w(stream, sa_kw, sqkvt + 256 * 256,   256, 256, NLAYERS_, 768 * 256);
  conv_w(stream, sa_vw, sqkvt + 512 * 256,   256, 256, NLAYERS_, 768 * 256);
  conv_w(stream, sa_ow, sowt, 256, 256, NLAYERS_, 256 * 256);
  conv_w(stream, off_w, soffawt,             256, 192, NLAYERS_, 288 * 256);
  conv_w(stream, aw_w,  soffawt + 192 * 256, 256,  96, NLAYERS_, 288 * 256);
  conv_w(stream, gate_w, gatet, 512, 512, NLAYERS_, 512 * 512);
  conv_w(stream, ff1_w, ff1t, 256, 1024, NLAYERS_, 1024 * 256);
  conv_w(stream, ff2_w, ff2t, 1024, 256, NLAYERS_, 256 * 1024);
  conv_w(stream, bb_w1, bb1t, 256, 256, NLAYERS_, 256 * 256);
  conv_w(stream, bb_w2, bb2t, 256, 256, NLAYERS_, 256 * 256);
  conv_w(stream, bb_w3, bb3t, 256, 132, NLAYERS_, 144 * 256);
  conv_w(stream, pb_w1, pb1t, 256, 256, 1, 0);
  conv_w(stream, pb_w2, pb2t, 256, 256, 1, 0);
  conv_w(stream, pb_w3, pb3t, 256, 4, 1, 0);
  conv_w(stream, sc_w + (size_t)5 * D_ * NC_, sct, 256, 80, 1, 0);
  bcat_kernel<<<egrid(NLAYERS_ * 768), 256, 0, stream>>>(sa_qb, sa_kb, sa_vb, off_b, aw_b,
                                                         qkvb, offawb);
  if (bf16mem)
    memconv_kernel<<<dim3(B_ * STOT_ / 4), 256, 0, stream>>>(memory, membf);

  // ---- init ----
  fill0_kernel<<<egrid(R_ * D_), 256, 0, stream>>>(out_prev, R_ * D_);
  fill0_kernel<<<egrid(R_ * 4 * NBIN_), 256, 0, stream>>>(c_prev, R_ * 4 * NBIN_);
  sigmoid_kernel<<<egrid(R_ * 4), 256, 0, stream>>>(ref_cur, ref_unact, R_ * 4);
  initcvt_kernel<<<egrid(R_ * D_ / 4), 256, 0, stream>>>(output, outbf, target, R_ * D_ / 4);

  for (int i = 0; i < NLAYERS_; ++i) {
    // qp MLP (fused both layers); oqbf = bf16(output + qp)
    qp_mlp<<<dim3(75), 256, 0, stream>>>(ref_cur, qp_w1, qp_b1, qp2t, qp_b2,
                                         output, qp, oqbf);

    // ---- self attention ----
    launch_bgemm(stream, oqbf, outbf, 512, nullptr, 0, sqkvt + (size_t)i * 768 * 256,
                 qkvb + (size_t)i * 768, nullptr, nullptr, qkv, R_, 768, 256, 0);
    attn3_kernel<<<dim3(B_ * NH_ * 2), 256, 0, stream>>>(qkv, tbf);
    // sow GEMM + ln0 fused; oqbf = bf16(v + qp)
    gemm_ln<256, 0><<<dim3(150), 256, 0, stream>>>(
        tbf, sowt + (size_t)i * 65536, sa_ob + (size_t)i * D_, output,
        n1_g + (size_t)i * D_, n1_b + (size_t)i * D_, qp, nullptr,
        output, outbf, oqbf);

    // ---- deformable cross attention ----
    launch_bgemm(stream, oqbf, nullptr, 0, nullptr, 0, soffawt + (size_t)i * 288 * 256,
                 offawb + (size_t)i * 288, nullptr, offawf, nullptr, R_, 288, 256, 0);
    if (bf16mem)
      deform_kernel<1><<<dim3(R_), 256, 0, stream>>>(membf, offawf, ref_cur, t2, tbf);
    else
      deform_kernel<0><<<dim3(R_), 256, 0, stream>>>(memory, offawf, ref_cur, t2, tbf);

    // ---- gateway ----
    launch_bgemm(stream, outbf, nullptr, 0, tbf, 256, gatet + (size_t)i * 262144,
                 gate_b + (size_t)i * 512, nullptr, g12, nullptr, R_, 512, 512, 3);
    ln2_kernel<<<dim3(R_), 256, 0, stream>>>(output, outbf, output, t2, g12,
                                             gn_g + (size_t)i * D_, gn_b + (size_t)i * D_);

    // ---- FFN ----
    launch_bgemm(stream, outbf, nullptr, 0, nullptr, 0, ff1t + (size_t)i * 262144,
                 ff1_b + (size_t)i * FF_, nullptr, nullptr, ffnhid, R_, FF_, 256, 1);
    // ff2 GEMM + ln1 fused; oqbf = bf16(v + out_prev_old); out_prev = v
    gemm_ln<1024, 1><<<dim3(150), 256, 0, stream>>>(
        ffnhid, ff2t + (size_t)i * 262144, ff2_b + (size_t)i * D_, output,
        n3_g + (size_t)i * D_, n3_b + (size_t)i * D_, nullptr, out_prev,
        output, outbf, oqbf);

    // ---- FDR box refinement ----
    if (i == 0) {
      launch_bgemm(stream, outbf, nullptr, 0, nullptr, 0, pb1t, pb_b1, nullptr,
                   nullptr, h1bf, R_, D_, 256, 2);
      launch_bgemm(stream, h1bf, nullptr, 0, nullptr, 0, pb2t, pb_b2, nullptr,
                   nullptr, h2bf, R_, D_, 256, 2);
      pb3_prebb<<<egrid(R_ * 4), 256, 0, stream>>>(h2bf, pb3t, pb_b3, ref_cur, ref_init);
    }
    launch_bgemm(stream, oqbf, nullptr, 0, nullptr, 0, bb1t + (size_t)i * 65536,
                 bb_b1 + (size_t)i * D_, nullptr, nullptr, h1bf, R_, D_, 256, 2);
    launch_bgemm(stream, h1bf, nullptr, 0, nullptr, 0, bb2t + (size_t)i * 65536,
                 bb_b2 + (size_t)i * D_, nullptr, nullptr, h2bf, R_, D_, 256, 2);
    bb3_bbox<<<dim3(75), 256, 0, stream>>>(h2bf, bb3t + (size_t)i * 144 * 256,
                                           bb_b3 + (size_t)i * 4 * NBIN_,
                                           c_prev, c_cur, ref_init, ref_nxt);

    if (i == NLAYERS_ - 1) {
      launch_bgemm(stream, outbf, nullptr, 0, nullptr, 0, sct, sc_b + (size_t)5 * NC_,
                   nullptr, scores, nullptr, R_, NC_, 256, 0);
      lqe_kernel<<<dim3(R_), 64, 0, stream>>>(scores, c_cur,
                                              lqe_w1 + (size_t)5 * 20 * 64, lqe_b1 + (size_t)5 * 64,
                                              lqe_w2 + (size_t)5 * 64, lqe_b2 + (size_t)5,
                                              ref_nxt, out);
    } else {
      std::swap(c_prev, c_cur);
      std::swap(ref_cur, ref_nxt);
    }
  }
}

// Round 6
// 2073.445 us; speedup vs baseline: 1.2868x; 1.2868x over previous
//
#include <hip/hip_runtime.h>
#include <cstddef>
#include <cmath>
#include <utility>

#define B_ 16
#define LQ_ 300
#define D_ 256
#define NH_ 8
#define HD_ 32
#define FF_ 1024
#define NBIN_ 33
#define NC_ 80
#define SUMP_ 12
#define TOT_ (NH_*SUMP_)   // 96
#define STOT_ 8400
#define R_ (B_*LQ_)        // 4800
#define NLAYERS_ 6

typedef short bf16x8 __attribute__((ext_vector_type(8)));
typedef float f32x4  __attribute__((ext_vector_type(4)));

static __device__ __forceinline__ short f2bf(float x) {
  union { float f; unsigned u; } v; v.f = x;
  unsigned r = v.u + 0x7fffu + ((v.u >> 16) & 1u);   // RNE
  return (short)(r >> 16);
}
static __device__ __forceinline__ float bf2f(short s) {
  union { unsigned u; float f; } v; v.u = ((unsigned)(unsigned short)s) << 16; return v.f;
}

// ---------------------------------------------------------------------------
// Weight convert+transpose: W [K,N] fp32 -> Wt [N,K] bf16 at out-stride.
// ---------------------------------------------------------------------------
__launch_bounds__(256)
__global__ void wconv_kernel(const float* __restrict__ W, short* __restrict__ Wt,
                             int K, int N, size_t ostride) {
  __shared__ float t[32][33];
  const float* Wl = W + (size_t)blockIdx.z * K * N;
  short* Wtl = Wt + (size_t)blockIdx.z * ostride;
  int k0 = blockIdx.x * 32, n0 = blockIdx.y * 32;
  int tr = threadIdx.x >> 5, tc = threadIdx.x & 31;
  #pragma unroll
  for (int i = 0; i < 4; ++i) {
    int k = k0 + tr + i * 8, n = n0 + tc;
    t[tr + i * 8][tc] = (k < K && n < N) ? Wl[(size_t)k * N + n] : 0.f;
  }
  __syncthreads();
  #pragma unroll
  for (int i = 0; i < 4; ++i) {
    int n = n0 + tr + i * 8, k = k0 + tc;
    if (n < N && k < K) Wtl[(size_t)n * K + k] = f2bf(t[tc][tr + i * 8]);
  }
}

// memory fp32 [B,S,256] -> bf16 head-major [B,NH,S,32]
__launch_bounds__(256)
__global__ void memconv_kernel(const float* __restrict__ mem, short* __restrict__ mb) {
  int gs = blockIdx.x * 4 + (threadIdx.x >> 6);
  int c  = (threadIdx.x & 63) * 4;
  int b = gs / STOT_, s = gs - b * STOT_;
  float4 v = *(const float4*)(mem + (size_t)gs * 256 + c);
  int h = c >> 5, cc = c & 31;
  short4 o; o.x = f2bf(v.x); o.y = f2bf(v.y); o.z = f2bf(v.z); o.w = f2bf(v.w);
  *(short4*)(mb + (((size_t)(b * 8 + h) * STOT_ + s) * 32) + cc) = o;
}

// ---------------------------------------------------------------------------
// Barrier-free bf16 MFMA GEMM, templated K.
// ACT: 0 none,1 relu,2 silu,3 sigmoid,4 clip10
// ---------------------------------------------------------------------------
template<int ACT, int KT>
__launch_bounds__(256)
__global__ void bgemm(const short* __restrict__ A, const short* __restrict__ A2, int N2,
                      const short* __restrict__ Acat, int KA,
                      const short* __restrict__ Wt, const float* __restrict__ bias,
                      const float* __restrict__ Cadd, float* __restrict__ Cf,
                      short* __restrict__ Cbf, int M, int N) {
  const int bm = blockIdx.y * 64, bn = blockIdx.x * 64;
  const int tid = threadIdx.x, wid = tid >> 6, lane = tid & 63;
  const int wm = (wid >> 1) * 32, wn = (wid & 1) * 32;
  const int lr = lane & 15, lq = lane >> 4;
  const short* Ab = (A2 && bn >= N2) ? A2 : A;
  const int lda = Acat ? KA : KT;
  const int ldb = KT - KA;
  const int r0 = bm + wm + lr, r1 = r0 + 16;
  const int n0 = bn + wn + lr, n1 = n0 + 16;
  const bool v0 = n0 < N, v1 = n1 < N;
  const short* w0p = Wt + (size_t)(v0 ? n0 : 0) * KT + lq * 8;
  const short* w1p = Wt + (size_t)(v1 ? n1 : 0) * KT + lq * 8;
  f32x4 acc[2][2];
  #pragma unroll
  for (int i = 0; i < 2; ++i)
    #pragma unroll
    for (int j = 0; j < 2; ++j) acc[i][j] = (f32x4){0.f, 0.f, 0.f, 0.f};

  #pragma unroll 4
  for (int k0 = 0; k0 < KT; k0 += 32) {
    const short* src; int ko, ld;
    if (Acat && k0 >= KA) { src = Acat; ko = k0 - KA; ld = ldb; }
    else                  { src = Ab;   ko = k0;      ld = lda; }
    bf16x8 a0 = *(const bf16x8*)(src + (size_t)r0 * ld + ko + lq * 8);
    bf16x8 a1 = *(const bf16x8*)(src + (size_t)r1 * ld + ko + lq * 8);
    bf16x8 w0 = *(const bf16x8*)(w0p + k0);
    bf16x8 w1 = *(const bf16x8*)(w1p + k0);
    acc[0][0] = __builtin_amdgcn_mfma_f32_16x16x32_bf16(a0, w0, acc[0][0], 0, 0, 0);
    acc[0][1] = __builtin_amdgcn_mfma_f32_16x16x32_bf16(a0, w1, acc[0][1], 0, 0, 0);
    acc[1][0] = __builtin_amdgcn_mfma_f32_16x16x32_bf16(a1, w0, acc[1][0], 0, 0, 0);
    acc[1][1] = __builtin_amdgcn_mfma_f32_16x16x32_bf16(a1, w1, acc[1][1], 0, 0, 0);
  }
  #pragma unroll
  for (int ti = 0; ti < 2; ++ti)
    #pragma unroll
    for (int tj = 0; tj < 2; ++tj) {
      int gn = bn + wn + tj * 16 + lr;
      if (gn >= N) continue;
      float bv = bias[gn];
      #pragma unroll
      for (int r = 0; r < 4; ++r) {
        int gm = bm + wm + ti * 16 + lq * 4 + r;
        size_t idx = (size_t)gm * N + gn;
        float v = acc[ti][tj][r] + bv;
        if (Cadd) v += Cadd[idx];
        if (ACT == 1) v = fmaxf(v, 0.f);
        if (ACT == 2) v = v / (1.f + __expf(-v));
        if (ACT == 3) v = 1.f / (1.f + __expf(-v));
        if (ACT == 4) v = fminf(fmaxf(v, -10.f), 10.f);
        if (Cf)  Cf[idx] = v;
        if (Cbf) Cbf[idx] = f2bf(v);
      }
    }
}

// ---------------------------------------------------------------------------
// Fused GEMM (N=256) + LayerNorm. Block = 16 rows x 256 cols, 4 waves
// (wave = 16 rows x 64 cols = 4 mfma tiles). Grid = 300.
// x = resid + (A@Wt + bias)  [MODE1: clip +-65504]
// v = LN(x)*gamma+beta -> out(fp32), outbf(bf16)
// MODE0: oqbf = bf16(v + qp)   MODE1: oqbf = bf16(v + prev_old); prev = v
// ---------------------------------------------------------------------------
template<int KT, int MODE>
__launch_bounds__(256)
__global__ void gemm_ln(const short* __restrict__ A, const short* __restrict__ Wt,
                        const float* __restrict__ bias, const float* __restrict__ resid,
                        const float* __restrict__ gamma, const float* __restrict__ beta,
                        const float* __restrict__ qp, float* __restrict__ prev,
                        float* __restrict__ outf, short* __restrict__ outbf,
                        short* __restrict__ oqbf) {
  __shared__ float ssum[16][4];
  __shared__ float ssq[16][4];
  const int m0 = blockIdx.x * 16;
  const int tid = threadIdx.x, wid = tid >> 6, lane = tid & 63;
  const int lr = lane & 15, lq = lane >> 4;
  const int arow = m0 + lr;
  const int cw = wid * 64;
  f32x4 acc[4];
  #pragma unroll
  for (int t = 0; t < 4; ++t) acc[t] = (f32x4){0.f, 0.f, 0.f, 0.f};
  #pragma unroll 4
  for (int k0 = 0; k0 < KT; k0 += 32) {
    bf16x8 a = *(const bf16x8*)(A + (size_t)arow * KT + k0 + lq * 8);
    #pragma unroll
    for (int t = 0; t < 4; ++t) {
      bf16x8 w = *(const bf16x8*)(Wt + (size_t)(cw + t * 16 + lr) * KT + k0 + lq * 8);
      acc[t] = __builtin_amdgcn_mfma_f32_16x16x32_bf16(a, w, acc[t], 0, 0, 0);
    }
  }
  float s[4] = {0.f, 0.f, 0.f, 0.f}, q[4] = {0.f, 0.f, 0.f, 0.f};
  #pragma unroll
  for (int t = 0; t < 4; ++t) {
    int col = cw + t * 16 + lr;
    float bv = bias[col];
    #pragma unroll
    for (int rr = 0; rr < 4; ++rr) {
      int rowg = m0 + lq * 4 + rr;
      float x = acc[t][rr] + bv + resid[(size_t)rowg * 256 + col];
      if (MODE == 1) x = fminf(fmaxf(x, -65504.f), 65504.f);
      acc[t][rr] = x;
      s[rr] += x; q[rr] += x * x;
    }
  }
  #pragma unroll
  for (int m = 1; m < 16; m <<= 1)
    #pragma unroll
    for (int rr = 0; rr < 4; ++rr) { s[rr] += __shfl_xor(s[rr], m); q[rr] += __shfl_xor(q[rr], m); }
  if (lr == 0)
    #pragma unroll
    for (int rr = 0; rr < 4; ++rr) {
      ssum[lq * 4 + rr][wid] = s[rr];
      ssq[lq * 4 + rr][wid] = q[rr];
    }
  __syncthreads();
  float mu[4], rs[4];
  #pragma unroll
  for (int rr = 0; rr < 4; ++rr) {
    int rl = lq * 4 + rr;
    float sm = ssum[rl][0] + ssum[rl][1] + ssum[rl][2] + ssum[rl][3];
    float sq = ssq[rl][0] + ssq[rl][1] + ssq[rl][2] + ssq[rl][3];
    float m_ = sm * (1.f / 256.f);
    float var = sq * (1.f / 256.f) - m_ * m_;
    mu[rr] = m_; rs[rr] = rsqrtf(var + 1e-5f);
  }
  #pragma unroll
  for (int t = 0; t < 4; ++t) {
    int col = cw + t * 16 + lr;
    float g = gamma[col], be = beta[col];
    #pragma unroll
    for (int rr = 0; rr < 4; ++rr) {
      int rowg = m0 + lq * 4 + rr;
      size_t idx = (size_t)rowg * 256 + col;
      float v = (acc[t][rr] - mu[rr]) * rs[rr] * g + be;
      outf[idx] = v;
      outbf[idx] = f2bf(v);
      if (MODE == 0) {
        oqbf[idx] = f2bf(v + qp[idx]);
      } else {
        float po = prev[idx];
        oqbf[idx] = f2bf(v + po);
        prev[idx] = v;
      }
    }
  }
}

// ---------------------------------------------------------------------------
// Fused gateway GEMM + sigmoid + gated-add + LayerNorm. Block = 16 rows,
// 4 waves (wave = 16 x 128 = 8 tiles), grid 300. K=512 concat (outbf|tbf).
// ---------------------------------------------------------------------------
__launch_bounds__(256)
__global__ void gate_ln(const short* __restrict__ Abf, const short* __restrict__ tbf,
                        const short* __restrict__ Wt, const float* __restrict__ bias,
                        const float* __restrict__ t2,
                        const float* __restrict__ gamma, const float* __restrict__ beta,
                        float* __restrict__ output, short* __restrict__ outbf) {
  __shared__ float sg[16][520];
  const int m0 = blockIdx.x * 16;
  const int tid = threadIdx.x, wid = tid >> 6, lane = tid & 63;
  const int lr = lane & 15, lq = lane >> 4;
  const int arow = m0 + lr;
  f32x4 acc[8];
  #pragma unroll
  for (int t = 0; t < 8; ++t) acc[t] = (f32x4){0.f, 0.f, 0.f, 0.f};
  #pragma unroll 2
  for (int k0 = 0; k0 < 512; k0 += 32) {
    const short* src = (k0 < 256) ? Abf : tbf;
    int ko = (k0 < 256) ? k0 : k0 - 256;
    bf16x8 a = *(const bf16x8*)(src + (size_t)arow * 256 + ko + lq * 8);
    #pragma unroll
    for (int t = 0; t < 8; ++t) {
      bf16x8 w = *(const bf16x8*)(Wt + (size_t)(wid * 128 + t * 16 + lr) * 512 + k0 + lq * 8);
      acc[t] = __builtin_amdgcn_mfma_f32_16x16x32_bf16(a, w, acc[t], 0, 0, 0);
    }
  }
  #pragma unroll
  for (int t = 0; t < 8; ++t) {
    int col = wid * 128 + t * 16 + lr;
    float bv = bias[col];
    #pragma unroll
    for (int rr = 0; rr < 4; ++rr) {
      int rl = lq * 4 + rr;
      sg[rl][col] = 1.f / (1.f + __expf(-(acc[t][rr] + bv)));
    }
  }
  __syncthreads();
  // LN phase: wave w handles rows w, w+4, w+8, w+12; lane covers 4 cols.
  #pragma unroll
  for (int it = 0; it < 4; ++it) {
    int rl = wid + it * 4;
    int rowg = m0 + rl;
    int c = lane * 4;
    float4 o4 = *(const float4*)(output + (size_t)rowg * 256 + c);
    float4 t4 = *(const float4*)(t2 + (size_t)rowg * 256 + c);
    float4 g1 = *(const float4*)&sg[rl][c];
    float4 g2 = *(const float4*)&sg[rl][256 + c];
    float x0 = g1.x * o4.x + g2.x * t4.x;
    float x1 = g1.y * o4.y + g2.y * t4.y;
    float x2 = g1.z * o4.z + g2.z * t4.z;
    float x3 = g1.w * o4.w + g2.w * t4.w;
    float s = x0 + x1 + x2 + x3;
    float q = x0 * x0 + x1 * x1 + x2 * x2 + x3 * x3;
    #pragma unroll
    for (int o = 32; o; o >>= 1) { s += __shfl_xor(s, o); q += __shfl_xor(q, o); }
    float mu = s * (1.f / 256.f);
    float var = q * (1.f / 256.f) - mu * mu;
    float rs = rsqrtf(var + 1e-5f);
    float4 ga = *(const float4*)(gamma + c);
    float4 be = *(const float4*)(beta + c);
    float v0 = (x0 - mu) * rs * ga.x + be.x;
    float v1 = (x1 - mu) * rs * ga.y + be.y;
    float v2 = (x2 - mu) * rs * ga.z + be.z;
    float v3 = (x3 - mu) * rs * ga.w + be.w;
    float4 vo; vo.x = v0; vo.y = v1; vo.z = v2; vo.w = v3;
    *(float4*)(output + (size_t)rowg * 256 + c) = vo;
    short4 vs; vs.x = f2bf(v0); vs.y = f2bf(v1); vs.z = f2bf(v2); vs.w = f2bf(v3);
    *(short4*)(outbf + (size_t)rowg * 256 + c) = vs;
  }
}

// ---------------------------------------------------------------------------
// Fused qp MLP: hid(16 rows) in LDS; qp = clip(hid@W2t+b2);
// oqbf = bf16(qp + output). Block = 16 rows, grid 300.
// ---------------------------------------------------------------------------
__launch_bounds__(256)
__global__ void qp_mlp(const float* __restrict__ ref, const float* __restrict__ W1,
                       const float* __restrict__ b1, const short* __restrict__ W2t,
                       const float* __restrict__ b2, const float* __restrict__ output,
                       float* __restrict__ qpout, short* __restrict__ oqbf) {
  __shared__ short sh[16 * 520];
  const int m0 = blockIdx.x * 16;
  const int tid = threadIdx.x;
  for (int i = tid; i < 16 * 512; i += 256) {
    int r = i >> 9, n = i & 511;
    float4 rv = *(const float4*)(ref + (size_t)(m0 + r) * 4);
    float v = b1[n] + rv.x * W1[n] + rv.y * W1[512 + n] + rv.z * W1[1024 + n]
            + rv.w * W1[1536 + n];
    v = v / (1.f + __expf(-v));
    sh[r * 520 + n] = f2bf(v);
  }
  __syncthreads();
  const int wid = tid >> 6, lane = tid & 63;
  const int lr = lane & 15, lq = lane >> 4;
  f32x4 acc[4];
  #pragma unroll
  for (int t = 0; t < 4; ++t) acc[t] = (f32x4){0.f, 0.f, 0.f, 0.f};
  #pragma unroll 4
  for (int k0 = 0; k0 < 512; k0 += 32) {
    bf16x8 a = *(const bf16x8*)&sh[lr * 520 + k0 + lq * 8];
    #pragma unroll
    for (int t = 0; t < 4; ++t) {
      bf16x8 w = *(const bf16x8*)(W2t + (size_t)(wid * 64 + t * 16 + lr) * 512 + k0 + lq * 8);
      acc[t] = __builtin_amdgcn_mfma_f32_16x16x32_bf16(a, w, acc[t], 0, 0, 0);
    }
  }
  #pragma unroll
  for (int t = 0; t < 4; ++t) {
    int col = wid * 64 + t * 16 + lr;
    float bv = b2[col];
    #pragma unroll
    for (int rr = 0; rr < 4; ++rr) {
      int rowg = m0 + lq * 4 + rr;
      size_t idx = (size_t)rowg * 256 + col;
      float v = fminf(fmaxf(acc[t][rr] + bv, -10.f), 10.f);
      qpout[idx] = v;
      oqbf[idx] = f2bf(v + output[idx]);
    }
  }
}

// ---------------------------------------------------------------------------
// pb3 (N=4) + prebb fused: ref_init = sigmoid(h2@pb3 + b + inv_sigmoid(ref))
// ---------------------------------------------------------------------------
__launch_bounds__(256)
__global__ void pb3_prebb(const short* __restrict__ A, const short* __restrict__ Wt,
                          const float* __restrict__ bias, const float* __restrict__ refc,
                          float* __restrict__ refinit) {
  int i = blockIdx.x * 256 + threadIdx.x;
  if (i >= R_ * 4) return;
  int row = i >> 2, n = i & 3;
  const short* ap = A + (size_t)row * 256;
  const short* wp = Wt + (size_t)n * 256;
  float dot = 0.f;
  #pragma unroll 8
  for (int k = 0; k < 256; ++k) dot += bf2f(ap[k]) * bf2f(wp[k]);
  float pre = dot + bias[n];
  float x = fminf(fmaxf(refc[i], 1e-5f), 1.f - 1e-5f);
  float is = logf(x) - log1pf(-x);
  refinit[i] = 1.f / (1.f + __expf(-(pre + is)));
}

// ---------------------------------------------------------------------------
// corners -> dist -> distance2bbox
// ---------------------------------------------------------------------------
__launch_bounds__(256)
__global__ void bbox_kernel(const float* __restrict__ corners, const float* __restrict__ refi,
                            float* __restrict__ inter) {
  int row = blockIdx.x * blockDim.x + threadIdx.x;
  if (row >= R_) return;
  float proj[NBIN_];
  proj[0] = -4.f; proj[16] = 0.f; proj[32] = 4.f;
  const float step = powf(3.f, 1.f / 15.f);
  float pw = 1.f;
  for (int i = 1; i <= 15; ++i) { pw *= step; proj[16 + i] = pw - 1.f; proj[16 - i] = 1.f - pw; }
  float dist[4];
  for (int s = 0; s < 4; ++s) {
    const float* cp = corners + (size_t)row * (4 * NBIN_) + s * NBIN_;
    float m = -1e30f;
    for (int j = 0; j < NBIN_; ++j) m = fmaxf(m, cp[j]);
    float sum = 0.f, dot = 0.f;
    for (int j = 0; j < NBIN_; ++j) { float e = __expf(cp[j] - m); sum += e; dot += e * proj[j]; }
    dist[s] = dot / sum;
  }
  float px = refi[row * 4], py = refi[row * 4 + 1];
  float qw = refi[row * 4 + 2] * 0.25f, qh = refi[row * 4 + 3] * 0.25f;
  float x1 = px - (2.f + dist[0]) * qw, y1 = py - (2.f + dist[1]) * qh;
  float x2 = px + (2.f + dist[2]) * qw, y2 = py + (2.f + dist[3]) * qh;
  inter[row * 4 + 0] = (x1 + x2) * 0.5f;
  inter[row * 4 + 1] = (y1 + y2) * 0.5f;
  inter[row * 4 + 2] = x2 - x1;
  inter[row * 4 + 3] = y2 - y1;
}

// ---------------------------------------------------------------------------
// MFMA self-attention. Block per (b,h,half).
// ---------------------------------------------------------------------------
__launch_bounds__(256)
__global__ void attn3_kernel(const short* __restrict__ qkv, short* __restrict__ O) {
  __shared__ short Kb[304][40];
  __shared__ short Vt[32][328];
  __shared__ short Pw[4][16][328];
  const int half = blockIdx.x & 1, bh = blockIdx.x >> 1;
  const int h = bh & 7, b = bh >> 3;
  const int tid = threadIdx.x;
  const short* QKVb = qkv + (size_t)b * LQ_ * 768;
  for (int idx = tid; idx < 304 * 4; idx += 256) {
    int row = idx >> 2, seg = (idx & 3) * 8;
    bf16x8 v = (row < 300) ? *(const bf16x8*)(QKVb + (size_t)row * 768 + 256 + h * 32 + seg)
                           : (bf16x8){0,0,0,0,0,0,0,0};
    *(bf16x8*)&Kb[row][seg] = v;
  }
  for (int idx = tid; idx < 300 * 4; idx += 256) {
    int row = idx >> 2, seg = (idx & 3) * 8;
    bf16x8 v = *(const bf16x8*)(QKVb + (size_t)row * 768 + 512 + h * 32 + seg);
    #pragma unroll
    for (int j = 0; j < 8; ++j) Vt[seg + j][row] = v[j];
  }
  for (int idx = tid; idx < 32 * 20; idx += 256) Vt[idx / 20][300 + idx % 20] = 0;
  for (int idx = tid; idx < 4 * 16 * 16; idx += 256)
    Pw[idx >> 8][(idx >> 4) & 15][304 + (idx & 15)] = 0;
  __syncthreads();

  const int wid = tid >> 6, lane = tid & 63;
  const int lr = lane & 15, lq = lane >> 4;
  short (*Pl)[328] = Pw[wid];
  const float scale = 0.17677669529663687f;

  for (int qt = wid; qt < 10; qt += 4) {
    const int q0 = half * 150 + qt * 16;
    int qrow = q0 + lr; if (qrow > 299) qrow = 299;
    bf16x8 af_q = *(const bf16x8*)(QKVb + (size_t)qrow * 768 + h * 32 + lq * 8);
    f32x4 s[19];
    #pragma unroll
    for (int t = 0; t < 19; ++t) {
      bf16x8 bk = *(const bf16x8*)&Kb[t * 16 + lr][lq * 8];
      s[t] = __builtin_amdgcn_mfma_f32_16x16x32_bf16(af_q, bk, (f32x4){0.f,0.f,0.f,0.f}, 0, 0, 0);
    }
    #pragma unroll
    for (int t = 0; t < 19; ++t)
      #pragma unroll
      for (int r = 0; r < 4; ++r) s[t][r] *= scale;
    if (lr >= 12) { s[18][0] = s[18][1] = s[18][2] = s[18][3] = -1e30f; }
    float l[4];
    #pragma unroll
    for (int r = 0; r < 4; ++r) {
      float mm = -1e30f;
      #pragma unroll
      for (int t = 0; t < 19; ++t) mm = fmaxf(mm, s[t][r]);
      #pragma unroll
      for (int x = 1; x < 16; x <<= 1) mm = fmaxf(mm, __shfl_xor(mm, x));
      float ll = 0.f;
      #pragma unroll
      for (int t = 0; t < 19; ++t) { float p = __expf(s[t][r] - mm); s[t][r] = p; ll += p; }
      #pragma unroll
      for (int x = 1; x < 16; x <<= 1) ll += __shfl_xor(ll, x);
      l[r] = ll;
    }
    #pragma unroll
    for (int t = 0; t < 19; ++t)
      #pragma unroll
      for (int r = 0; r < 4; ++r) Pl[lq * 4 + r][t * 16 + lr] = f2bf(s[t][r]);
    f32x4 o0 = (f32x4){0.f,0.f,0.f,0.f}, o1 = (f32x4){0.f,0.f,0.f,0.f};
    #pragma unroll
    for (int c = 0; c < 10; ++c) {
      bf16x8 ap = *(const bf16x8*)&Pl[lr][c * 32 + lq * 8];
      bf16x8 v0 = *(const bf16x8*)&Vt[lr][c * 32 + lq * 8];
      bf16x8 v1 = *(const bf16x8*)&Vt[16 + lr][c * 32 + lq * 8];
      o0 = __builtin_amdgcn_mfma_f32_16x16x32_bf16(ap, v0, o0, 0, 0, 0);
      o1 = __builtin_amdgcn_mfma_f32_16x16x32_bf16(ap, v1, o1, 0, 0, 0);
    }
    #pragma unroll
    for (int r = 0; r < 4; ++r) {
      int q = q0 + lq * 4 + r;
      if (q >= 300) continue;
      float inv = 1.f / l[r];
      size_t ob = (size_t)(b * LQ_ + q) * 256 + h * 32;
      O[ob + lr]      = f2bf(o0[r] * inv);
      O[ob + 16 + lr] = f2bf(o1[r] * inv);
    }
  }
}

// ---------------------------------------------------------------------------
// Deformable sampling, branch-free taps (clamped idx, zeroed weights).
// ---------------------------------------------------------------------------
template<int BF16MEM>
__launch_bounds__(256)
__global__ void deform_kernel(const void* __restrict__ memv, const float* __restrict__ offaw,
                              const float* __restrict__ refp,
                              float* __restrict__ t2, short* __restrict__ t2bf) {
  const int bi = blockIdx.x;
  const int row = (bi & 7) * 600 + (bi >> 3);   // XCD locality swizzle
  const int b = row / LQ_;
  const int tid = threadIdx.x;
  const int h = tid >> 5, c = tid & 31;
  const float rx = refp[row * 4 + 0], ry = refp[row * 4 + 1];
  const float rw = refp[row * 4 + 2], rh = refp[row * 4 + 3];
  const float* awp = offaw + (size_t)row * 288 + 192 + h * SUMP_;
  float wv[SUMP_];
  float wmax = -1e30f;
  #pragma unroll
  for (int p = 0; p < SUMP_; ++p) { wv[p] = awp[p]; wmax = fmaxf(wmax, wv[p]); }
  float wsum = 0.f;
  #pragma unroll
  for (int p = 0; p < SUMP_; ++p) { wv[p] = __expf(wv[p] - wmax); wsum += wv[p]; }
  const float winv = 1.f / wsum;
  const float* op = offaw + (size_t)row * 288 + h * (SUMP_ * 2);
  const short* mb16 = BF16MEM ? ((const short*)memv + ((size_t)(b * 8 + h) * STOT_) * 32 + c) : nullptr;
  const float* mb32 = BF16MEM ? nullptr : ((const float*)memv + (size_t)b * STOT_ * 256 + h * 32 + c);
  float acc = 0.f;
  #pragma unroll
  for (int p = 0; p < SUMP_; ++p) {
    const int lvl = p >> 2;
    const int Wl = (lvl == 0) ? 80 : ((lvl == 1) ? 40 : 20);
    const int s0 = (lvl == 0) ? 0 : ((lvl == 1) ? 6400 : 8000);
    float lx = rx + op[2 * p]     * 0.125f * rw;
    float ly = ry + op[2 * p + 1] * 0.125f * rh;
    float x = lx * Wl - 0.5f, y = ly * Wl - 0.5f;
    float xf = floorf(x), yf = floorf(y);
    int x0 = (int)xf, y0 = (int)yf;
    float wx = x - xf, wy = y - yf;
    int x0c = min(max(x0, 0), Wl - 1), x1c = min(max(x0 + 1, 0), Wl - 1);
    int y0c = min(max(y0, 0), Wl - 1), y1c = min(max(y0 + 1, 0), Wl - 1);
    float wx0 = (x0 >= 0 && x0 < Wl) ? (1.f - wx) : 0.f;
    float wx1 = (x0 + 1 >= 0 && x0 + 1 < Wl) ? wx : 0.f;
    float wy0 = (y0 >= 0 && y0 < Wl) ? (1.f - wy) : 0.f;
    float wy1 = (y0 + 1 >= 0 && y0 + 1 < Wl) ? wy : 0.f;
    float v;
    if (BF16MEM) {
      const short* mb = mb16 + (size_t)s0 * 32;
      v = wx0 * wy0 * bf2f(mb[(size_t)(y0c * Wl + x0c) * 32])
        + wx1 * wy0 * bf2f(mb[(size_t)(y0c * Wl + x1c) * 32])
        + wx0 * wy1 * bf2f(mb[(size_t)(y1c * Wl + x0c) * 32])
        + wx1 * wy1 * bf2f(mb[(size_t)(y1c * Wl + x1c) * 32]);
    } else {
      const float* mb = mb32 + (size_t)s0 * 256;
      v = wx0 * wy0 * mb[(size_t)(y0c * Wl + x0c) * 256]
        + wx1 * wy0 * mb[(size_t)(y0c * Wl + x1c) * 256]
        + wx0 * wy1 * mb[(size_t)(y1c * Wl + x0c) * 256]
        + wx1 * wy1 * mb[(size_t)(y1c * Wl + x1c) * 256];
    }
    acc += wv[p] * winv * v;
  }
  size_t off = (size_t)row * D_ + h * HD_ + c;
  t2[off] = acc;
  t2bf[off] = f2bf(acc);
}

// ---------------------------------------------------------------------------
// LQE head + final output assembly.
// ---------------------------------------------------------------------------
__launch_bounds__(64)
__global__ void lqe_kernel(const float* __restrict__ scores, const float* __restrict__ corners,
                           const float* __restrict__ w1, const float* __restrict__ b1,
                           const float* __restrict__ w2, const float* __restrict__ b2,
                           const float* __restrict__ inter, float* __restrict__ out) {
  const int row = blockIdx.x;
  const int tid = threadIdx.x;
  __shared__ float stat[20];
  __shared__ float lqe_s;
  if (tid < 4) {
    const float* cp = corners + (size_t)row * (4 * NBIN_) + tid * NBIN_;
    float m = -1e30f;
    for (int j = 0; j < NBIN_; ++j) m = fmaxf(m, cp[j]);
    float e[NBIN_]; float sum = 0.f;
    for (int j = 0; j < NBIN_; ++j) { e[j] = __expf(cp[j] - m); sum += e[j]; }
    float inv = 1.f / sum;
    float mean = 0.f;
    for (int t = 0; t < 4; ++t) {
      int bi = 0; float best = -1.f;
      for (int j = 0; j < NBIN_; ++j) if (e[j] > best) { best = e[j]; bi = j; }
      e[bi] = -2.f;
      float v = best * inv;
      stat[tid * 5 + t] = v; mean += v;
    }
    stat[tid * 5 + 4] = mean * 0.25f;
  }
  __syncthreads();
  float s = b1[tid];
  #pragma unroll
  for (int i = 0; i < 20; ++i) s += stat[i] * w1[i * 64 + tid];
  float hv = s / (1.f + __expf(-s));
  float v = hv * w2[tid];
  #pragma unroll
  for (int o = 32; o; o >>= 1) v += __shfl_down(v, o);
  if (tid == 0) lqe_s = v + b2[0];
  __syncthreads();
  if (tid < 4) out[(size_t)row * 84 + tid] = inter[row * 4 + tid];
  for (int c = tid; c < NC_; c += 64)
    out[(size_t)row * 84 + 4 + c] = scores[(size_t)row * NC_ + c] + lqe_s;
}

// ---------------------------------------------------------------------------
// small elementwise kernels
// ---------------------------------------------------------------------------
__global__ void fill0_kernel(float* __restrict__ p, int n) {
  int i = blockIdx.x * 256 + threadIdx.x; if (i < n) p[i] = 0.f;
}
__global__ void sigmoid_kernel(float* __restrict__ d, const float* __restrict__ s, int n) {
  int i = blockIdx.x * 256 + threadIdx.x; if (i < n) d[i] = 1.f / (1.f + __expf(-s[i]));
}
__global__ void initcvt_kernel(float* __restrict__ o, short* __restrict__ ob,
                               const float* __restrict__ t, int n4) {
  int i = blockIdx.x * 256 + threadIdx.x;
  if (i < n4) {
    float4 v = ((const float4*)t)[i];
    ((float4*)o)[i] = v;
    short4 s; s.x = f2bf(v.x); s.y = f2bf(v.y); s.z = f2bf(v.z); s.w = f2bf(v.w);
    ((short4*)ob)[i] = s;
  }
}
__global__ void bcat_kernel(const float* __restrict__ qb, const float* __restrict__ kb,
                            const float* __restrict__ vb, const float* __restrict__ ob,
                            const float* __restrict__ ab, float* __restrict__ qkvb,
                            float* __restrict__ offawb) {
  int i = blockIdx.x * 256 + threadIdx.x;
  if (i < NLAYERS_ * 768) {
    int l = i / 768, c = i % 768;
    qkvb[i] = (c < 256) ? qb[l * 256 + c] : (c < 512) ? kb[l * 256 + c - 256]
                        : vb[l * 256 + c - 512];
  }
  if (i < NLAYERS_ * 288) {
    int l = i / 288, c = i % 288;
    offawb[i] = (c < 192) ? ob[l * 192 + c] : ab[l * 96 + c - 192];
  }
}

// ---------------------------------------------------------------------------
// host orchestration
// ---------------------------------------------------------------------------
template<int KT>
static void launch_bgemm_k(hipStream_t st, const short* A, const short* A2, int N2,
                           const short* Acat, int KA, const short* Wt, const float* bias,
                           const float* Cadd, float* Cf, short* Cbf, int M, int N, int act) {
  dim3 g((N + 63) / 64, M / 64), blk(256);
  switch (act) {
    case 0: bgemm<0,KT><<<g, blk, 0, st>>>(A, A2, N2, Acat, KA, Wt, bias, Cadd, Cf, Cbf, M, N); break;
    case 1: bgemm<1,KT><<<g, blk, 0, st>>>(A, A2, N2, Acat, KA, Wt, bias, Cadd, Cf, Cbf, M, N); break;
    case 2: bgemm<2,KT><<<g, blk, 0, st>>>(A, A2, N2, Acat, KA, Wt, bias, Cadd, Cf, Cbf, M, N); break;
    case 3: bgemm<3,KT><<<g, blk, 0, st>>>(A, A2, N2, Acat, KA, Wt, bias, Cadd, Cf, Cbf, M, N); break;
    case 4: bgemm<4,KT><<<g, blk, 0, st>>>(A, A2, N2, Acat, KA, Wt, bias, Cadd, Cf, Cbf, M, N); break;
  }
}
static void launch_bgemm(hipStream_t st, const short* A, const short* A2, int N2,
                         const short* Acat, int KA, const short* Wt, const float* bias,
                         const float* Cadd, float* Cf, short* Cbf,
                         int M, int N, int K, int act) {
  if (K == 256)      launch_bgemm_k<256>(st, A, A2, N2, Acat, KA, Wt, bias, Cadd, Cf, Cbf, M, N, act);
  else if (K == 512) launch_bgemm_k<512>(st, A, A2, N2, Acat, KA, Wt, bias, Cadd, Cf, Cbf, M, N, act);
  else               launch_bgemm_k<1024>(st, A, A2, N2, Acat, KA, Wt, bias, Cadd, Cf, Cbf, M, N, act);
}

static void conv_w(hipStream_t st, const float* W, short* Wt, int K, int N, int L,
                   size_t ostride) {
  dim3 g((K + 31) / 32, (N + 31) / 32, L);
  wconv_kernel<<<g, 256, 0, st>>>(W, Wt, K, N, ostride);
}

static inline dim3 egrid(int n) { return dim3((n + 255) / 256); }

extern "C" void kernel_launch(void* const* d_in, const int* in_sizes, int n_in,
                              void* d_out, int out_size, void* d_ws, size_t ws_size,
                              hipStream_t stream) {
  const float* target     = (const float*)d_in[0];
  const float* ref_unact  = (const float*)d_in[1];
  const float* memory     = (const float*)d_in[2];
  const float* sa_qw = (const float*)d_in[3];  const float* sa_qb = (const float*)d_in[4];
  const float* sa_kw = (const float*)d_in[5];  const float* sa_kb = (const float*)d_in[6];
  const float* sa_vw = (const float*)d_in[7];  const float* sa_vb = (const float*)d_in[8];
  const float* sa_ow = (const float*)d_in[9];  const float* sa_ob = (const float*)d_in[10];
  const float* n1_g  = (const float*)d_in[11]; const float* n1_b  = (const float*)d_in[12];
  const float* off_w = (const float*)d_in[13]; const float* off_b = (const float*)d_in[14];
  const float* aw_w  = (const float*)d_in[15]; const float* aw_b  = (const float*)d_in[16];
  const float* gate_w= (const float*)d_in[17]; const float* gate_b= (const float*)d_in[18];
  const float* gn_g  = (const float*)d_in[19]; const float* gn_b  = (const float*)d_in[20];
  const float* ff1_w = (const float*)d_in[21]; const float* ff1_b = (const float*)d_in[22];
  const float* ff2_w = (const float*)d_in[23]; const float* ff2_b = (const float*)d_in[24];
  const float* n3_g  = (const float*)d_in[25]; const float* n3_b  = (const float*)d_in[26];
  const float* bb_w1 = (const float*)d_in[27]; const float* bb_b1 = (const float*)d_in[28];
  const float* bb_w2 = (const float*)d_in[29]; const float* bb_b2 = (const float*)d_in[30];
  const float* bb_w3 = (const float*)d_in[31]; const float* bb_b3 = (const float*)d_in[32];
  const float* sc_w  = (const float*)d_in[33]; const float* sc_b  = (const float*)d_in[34];
  const float* lqe_w1= (const float*)d_in[35]; const float* lqe_b1= (const float*)d_in[36];
  const float* lqe_w2= (const float*)d_in[37]; const float* lqe_b2= (const float*)d_in[38];
  const float* qp_w1 = (const float*)d_in[39]; const float* qp_b1 = (const float*)d_in[40];
  const float* qp_w2 = (const float*)d_in[41]; const float* qp_b2 = (const float*)d_in[42];
  const float* pb_w1 = (const float*)d_in[43]; const float* pb_b1 = (const float*)d_in[44];
  const float* pb_w2 = (const float*)d_in[45]; const float* pb_b2 = (const float*)d_in[46];
  const float* pb_w3 = (const float*)d_in[47]; const float* pb_b3 = (const float*)d_in[48];
  float* out = (float*)d_out;

  // ---- workspace: fp32 region ----
  float* ws = (float*)d_ws;
  size_t woff = 0;
  auto alloc = [&](size_t n) { float* p = ws + woff; woff += n; return p; };
  float* output   = alloc((size_t)R_ * D_);
  float* out_prev = alloc((size_t)R_ * D_);
  float* qp       = alloc((size_t)R_ * D_);
  float* t2       = alloc((size_t)R_ * D_);
  float* offawf   = alloc((size_t)R_ * 288);  // also scores
  float* U        = alloc((size_t)R_ * 512);  // qkv(bf)/ffnhid(bf)
  float* corners0 = alloc((size_t)R_ * 4 * NBIN_);
  float* corners1 = alloc((size_t)R_ * 4 * NBIN_);
  float* refA     = alloc((size_t)R_ * 4);
  float* refB     = alloc((size_t)R_ * 4);
  float* ref_init = alloc((size_t)R_ * 4);
  float* qkvb     = alloc((size_t)NLAYERS_ * 768);
  float* offawb   = alloc((size_t)NLAYERS_ * 288);

  // ---- workspace: bf16 region ----
  short* sws = (short*)(ws + woff);
  size_t soff = 0;
  auto salloc = [&](size_t n) { short* p = sws + soff; soff += n; return p; };
  short* outbf = salloc((size_t)R_ * D_);
  short* oqbf  = salloc((size_t)R_ * D_);
  short* tbf   = salloc((size_t)R_ * D_);
  short* h1bf  = salloc((size_t)R_ * D_);
  short* h2bf  = salloc((size_t)R_ * D_);
  short* qp2t  = salloc((size_t)256 * 512);
  short* sqkvt = salloc((size_t)NLAYERS_ * 768 * 256);
  short* sowt  = salloc((size_t)NLAYERS_ * 256 * 256);
  short* soffawt = salloc((size_t)NLAYERS_ * 288 * 256);
  short* gatet = salloc((size_t)NLAYERS_ * 512 * 512);
  short* ff1t  = salloc((size_t)NLAYERS_ * 1024 * 256);
  short* ff2t  = salloc((size_t)NLAYERS_ * 256 * 1024);
  short* bb1t  = salloc((size_t)NLAYERS_ * 256 * 256);
  short* bb2t  = salloc((size_t)NLAYERS_ * 256 * 256);
  short* bb3t  = salloc((size_t)NLAYERS_ * 132 * 256);
  short* pb1t  = salloc((size_t)256 * 256);
  short* pb2t  = salloc((size_t)256 * 256);
  short* pb3t  = salloc((size_t)4 * 256);
  short* sct   = salloc((size_t)80 * 256);
  size_t base_bytes = woff * sizeof(float) + soff * sizeof(short);
  if (ws_size < base_bytes) return;
  const size_t memn = (size_t)B_ * STOT_ * 256;
  bool bf16mem = (ws_size >= base_bytes + memn * sizeof(short));
  short* membf = sws + soff;

  short* qkv    = (short*)U;
  short* ffnhid = (short*)U;
  float* scores = offawf;

  float* c_prev = corners0; float* c_cur = corners1;
  float* ref_cur = refA;    float* ref_nxt = refB;

  // ---- weight prep ----
  conv_w(stream, qp_w2, qp2t, 512, 256, 1, 0);
  conv_w(stream, sa_qw, sqkvt,               256, 256, NLAYERS_, 768 * 256);
  conv_w(stream, sa_kw, sqkvt + 256 * 256,   256, 256, NLAYERS_, 768 * 256);
  conv_w(stream, sa_vw, sqkvt + 512 * 256,   256, 256, NLAYERS_, 768 * 256);
  conv_w(stream, sa_ow, sowt, 256, 256, NLAYERS_, 256 * 256);
  conv_w(stream, off_w, soffawt,             256, 192, NLAYERS_, 288 * 256);
  conv_w(stream, aw_w,  soffawt + 192 * 256, 256,  96, NLAYERS_, 288 * 256);
  conv_w(stream, gate_w, gatet, 512, 512, NLAYERS_, 512 * 512);
  conv_w(stream, ff1_w, ff1t, 256, 1024, NLAYERS_, 1024 * 256);
  conv_w(stream, ff2_w, ff2t, 1024, 256, NLAYERS_, 256 * 1024);
  conv_w(stream, bb_w1, bb1t, 256, 256, NLAYERS_, 256 * 256);
  conv_w(stream, bb_w2, bb2t, 256, 256, NLAYERS_, 256 * 256);
  conv_w(stream, bb_w3, bb3t, 256, 132, NLAYERS_, 132 * 256);
  conv_w(stream, pb_w1, pb1t, 256, 256, 1, 0);
  conv_w(stream, pb_w2, pb2t, 256, 256, 1, 0);
  conv_w(stream, pb_w3, pb3t, 256, 4, 1, 0);
  conv_w(stream, sc_w + (size_t)5 * D_ * NC_, sct, 256, 80, 1, 0);
  bcat_kernel<<<egrid(NLAYERS_ * 768), 256, 0, stream>>>(sa_qb, sa_kb, sa_vb, off_b, aw_b,
                                                         qkvb, offawb);
  if (bf16mem)
    memconv_kernel<<<dim3(B_ * STOT_ / 4), 256, 0, stream>>>(memory, membf);

  // ---- init ----
  fill0_kernel<<<egrid(R_ * D_), 256, 0, stream>>>(out_prev, R_ * D_);
  fill0_kernel<<<egrid(R_ * 4 * NBIN_), 256, 0, stream>>>(c_prev, R_ * 4 * NBIN_);
  sigmoid_kernel<<<egrid(R_ * 4), 256, 0, stream>>>(ref_cur, ref_unact, R_ * 4);
  initcvt_kernel<<<egrid(R_ * D_ / 4), 256, 0, stream>>>(output, outbf, target, R_ * D_ / 4);

  for (int i = 0; i < NLAYERS_; ++i) {
    // qp MLP (fused both layers); oqbf = bf16(output + qp)
    qp_mlp<<<dim3(300), 256, 0, stream>>>(ref_cur, qp_w1, qp_b1, qp2t, qp_b2,
                                          output, qp, oqbf);

    // ---- self attention ----
    launch_bgemm(stream, oqbf, outbf, 512, nullptr, 0, sqkvt + (size_t)i * 768 * 256,
                 qkvb + (size_t)i * 768, nullptr, nullptr, qkv, R_, 768, 256, 0);
    attn3_kernel<<<dim3(B_ * NH_ * 2), 256, 0, stream>>>(qkv, tbf);
    // sow GEMM + ln0 fused; oqbf = bf16(v + qp)
    gemm_ln<256, 0><<<dim3(300), 256, 0, stream>>>(
        tbf, sowt + (size_t)i * 65536, sa_ob + (size_t)i * D_, output,
        n1_g + (size_t)i * D_, n1_b + (size_t)i * D_, qp, nullptr,
        output, outbf, oqbf);

    // ---- deformable cross attention ----
    launch_bgemm(stream, oqbf, nullptr, 0, nullptr, 0, soffawt + (size_t)i * 288 * 256,
                 offawb + (size_t)i * 288, nullptr, offawf, nullptr, R_, 288, 256, 0);
    if (bf16mem)
      deform_kernel<1><<<dim3(R_), 256, 0, stream>>>(membf, offawf, ref_cur, t2, tbf);
    else
      deform_kernel<0><<<dim3(R_), 256, 0, stream>>>(memory, offawf, ref_cur, t2, tbf);

    // ---- gateway (GEMM + sigmoid + gated add + LN fused) ----
    gate_ln<<<dim3(300), 256, 0, stream>>>(outbf, tbf, gatet + (size_t)i * 262144,
                                           gate_b + (size_t)i * 512, t2,
                                           gn_g + (size_t)i * D_, gn_b + (size_t)i * D_,
                                           output, outbf);

    // ---- FFN ----
    launch_bgemm(stream, outbf, nullptr, 0, nullptr, 0, ff1t + (size_t)i * 262144,
                 ff1_b + (size_t)i * FF_, nullptr, nullptr, ffnhid, R_, FF_, 256, 1);
    // ff2 GEMM + ln1 fused; oqbf = bf16(v + out_prev_old); out_prev = v
    gemm_ln<1024, 1><<<dim3(300), 256, 0, stream>>>(
        ffnhid, ff2t + (size_t)i * 262144, ff2_b + (size_t)i * D_, output,
        n3_g + (size_t)i * D_, n3_b + (size_t)i * D_, nullptr, out_prev,
        output, outbf, oqbf);

    // ---- FDR box refinement ----
    if (i == 0) {
      launch_bgemm(stream, outbf, nullptr, 0, nullptr, 0, pb1t, pb_b1, nullptr,
                   nullptr, h1bf, R_, D_, 256, 2);
      launch_bgemm(stream, h1bf, nullptr, 0, nullptr, 0, pb2t, pb_b2, nullptr,
                   nullptr, h2bf, R_, D_, 256, 2);
      pb3_prebb<<<egrid(R_ * 4), 256, 0, stream>>>(h2bf, pb3t, pb_b3, ref_cur, ref_init);
    }
    launch_bgemm(stream, oqbf, nullptr, 0, nullptr, 0, bb1t + (size_t)i * 65536,
                 bb_b1 + (size_t)i * D_, nullptr, nullptr, h1bf, R_, D_, 256, 2);
    launch_bgemm(stream, h1bf, nullptr, 0, nullptr, 0, bb2t + (size_t)i * 65536,
                 bb_b2 + (size_t)i * D_, nullptr, nullptr, h2bf, R_, D_, 256, 2);
    launch_bgemm(stream, h2bf, nullptr, 0, nullptr, 0, bb3t + (size_t)i * 33792,
                 bb_b3 + (size_t)i * 4 * NBIN_, c_prev, c_cur, nullptr, R_, 4 * NBIN_, 256, 0);
    bbox_kernel<<<egrid(R_), 256, 0, stream>>>(c_cur, ref_init, ref_nxt);

    if (i == NLAYERS_ - 1) {
      launch_bgemm(stream, outbf, nullptr, 0, nullptr, 0, sct, sc_b + (size_t)5 * NC_,
                   nullptr, scores, nullptr, R_, NC_, 256, 0);
      lqe_kernel<<<dim3(R_), 64, 0, stream>>>(scores, c_cur,
                                              lqe_w1 + (size_t)5 * 20 * 64, lqe_b1 + (size_t)5 * 64,
                                              lqe_w2 + (size_t)5 * 64, lqe_b2 + (size_t)5,
                                              ref_nxt, out);
    } else {
      std::swap(c_prev, c_cur);
      std::swap(ref_cur, ref_nxt);
    }
  }
}